// Round 12
// baseline (202.715 us; speedup 1.0000x reference)
//
#include <hip/hip_runtime.h>
#include <hip/hip_bf16.h>
#include <cmath>

// B=4, S=1024, D_MODEL=1024, H=16, D_SP=512, DEPTH=64
// Inputs f32; outputs f32: out [4,1024,1024] then attn [4,16,1024,1024].

typedef __bf16 bf16x8 __attribute__((ext_vector_type(8)));
typedef __bf16 bf16x4 __attribute__((ext_vector_type(4)));
typedef float  f32x4  __attribute__((ext_vector_type(4)));

#define MFMA16(a, b, c) __builtin_amdgcn_mfma_f32_16x16x32_bf16((a), (b), (c), 0, 0, 0)

static constexpr int S = 1024, DM = 1024, H = 16, DEPTH = 64;

__device__ inline float wave_sum(float v) {
#pragma unroll
  for (int o = 32; o > 0; o >>= 1) v += __shfl_xor(v, o);
  return v;
}

// LDS-only barrier: waits ds ops, does NOT drain vmem stores (unlike __syncthreads).
__device__ inline void bar_lds() {
  __builtin_amdgcn_sched_barrier(0);
  asm volatile("s_waitcnt lgkmcnt(0)" ::: "memory");
  __builtin_amdgcn_s_barrier();
  __builtin_amdgcn_sched_barrier(0);
}

__device__ inline bf16x8 cvt8(const float* p) {
  float4 f0 = *reinterpret_cast<const float4*>(p);
  float4 f1 = *reinterpret_cast<const float4*>(p + 4);
  bf16x8 a = {(__bf16)f0.x, (__bf16)f0.y, (__bf16)f0.z, (__bf16)f0.w,
              (__bf16)f1.x, (__bf16)f1.y, (__bf16)f1.z, (__bf16)f1.w};
  return a;
}

// async global->LDS, 16 bytes per lane; lds dest = wave-uniform base + lane*16
__device__ inline void gl_lds16(const __bf16* g, void* l) {
  __builtin_amdgcn_global_load_lds(
      (const __attribute__((address_space(1))) unsigned int*)g,
      (__attribute__((address_space(3))) unsigned int*)l, 16, 0, 0);
}

// ---------------- prep: mdm/q/mask casts + all weight transposes ----------------
// blocks: 6144 casts + 896 transposes = 7040 total.
__device__ inline void tr_body(const float* __restrict__ W, __bf16* __restrict__ WT,
                               int K, int N, int bx, int by) {
  __shared__ float tile[64][65];
  int k0 = bx * 64, n0 = by * 64;
  int t = threadIdx.x;
  int r = t >> 2, c4 = (t & 3) * 16;
  const float* src = W + (size_t)(k0 + r) * N + n0 + c4;
#pragma unroll
  for (int j = 0; j < 4; j++) {
    float4 v = *reinterpret_cast<const float4*>(src + j * 4);
    tile[r][c4 + j * 4 + 0] = v.x;
    tile[r][c4 + j * 4 + 1] = v.y;
    tile[r][c4 + j * 4 + 2] = v.z;
    tile[r][c4 + j * 4 + 3] = v.w;
  }
  __syncthreads();
  __bf16* dst = WT + (size_t)(n0 + r) * K + k0 + c4;
  bf16x8 o0, o1;
#pragma unroll
  for (int j = 0; j < 8; j++) {
    o0[j] = (__bf16)tile[c4 + j][r];
    o1[j] = (__bf16)tile[c4 + 8 + j][r];
  }
  *reinterpret_cast<bf16x8*>(dst) = o0;
  *reinterpret_cast<bf16x8*>(dst + 8) = o1;
}

__global__ __launch_bounds__(256) void prep(
    const float* __restrict__ mdm, const float* __restrict__ q,
    const float* __restrict__ mask, const float* __restrict__ Wsp,
    const float* __restrict__ Wq, const float* __restrict__ Wk,
    const float* __restrict__ Wv, const float* __restrict__ Wo, __bf16* mdm_b,
    __bf16* q_b, __bf16* maskb, __bf16* WspT, __bf16* WqT, __bf16* WkT,
    __bf16* WvT, __bf16* WoT) {
  int id = blockIdx.x;
  if (id < 6144) {
    int i = id * 256 + threadIdx.x;
    if (i < 524288) {
      *reinterpret_cast<bf16x8*>(mdm_b + (size_t)i * 8) = cvt8(mdm + (size_t)i * 8);
    } else if (i < 1048576) {
      int j = i - 524288;
      *reinterpret_cast<bf16x8*>(q_b + (size_t)j * 8) = cvt8(q + (size_t)j * 8);
    } else {
      int j = i - 1048576;
      *reinterpret_cast<bf16x8*>(maskb + (size_t)j * 8) = cvt8(mask + (size_t)j * 8);
    }
    return;
  }
  id -= 6144;
  if (id < 128)      tr_body(Wsp, WspT, 1024, 512, id & 15, id >> 4);
  else if (id < 384) { id -= 128; tr_body(Wq, WqT, 1024, 1024, id & 15, id >> 4); }
  else if (id < 512) { id -= 384; tr_body(Wk, WkT, 512, 1024, id & 7, id >> 3); }
  else if (id < 640) { id -= 512; tr_body(Wv, WvT, 512, 1024, id & 7, id >> 3); }
  else               { id -= 640; tr_body(Wo, WoT, 1024, 1024, id & 15, id >> 4); }
}

// ---------------- pipelined LDS-staged GEMM, 512 threads (8 waves, 2x4 of 64x32) ----------------
// TM=128, TN=128, BK=32, double-buffered, 1 barrier/K-step.
// MODE 0: row-major out, bias. MODE 3: B rows<1024 -> kh (head-split), else vhT.
// MODE 4: blockIdx.x<4: sp=relu(A@BT) N=512; else qh from A2@BT2 (head-split).
template <int K, int MODE, typename OutT>
__global__ __launch_bounds__(512) void gemmL8(const __bf16* __restrict__ A,
                                              const __bf16* __restrict__ A2,
                                              const __bf16* __restrict__ BT,
                                              const __bf16* __restrict__ BT2,
                                              const float* __restrict__ bias,
                                              const float* __restrict__ bias2,
                                              OutT* __restrict__ out,
                                              OutT* __restrict__ out2, int N) {
  __shared__ __bf16 smA[2][128 * 32];
  __shared__ __bf16 smB[2][128 * 32];
  int tid = threadIdx.x, lane = tid & 63, wv = tid >> 6;
  int lr = lane & 15, hi = lane >> 4;
  int wr = (wv >> 2) * 64, wc = (wv & 3) * 32;
  int row0 = blockIdx.y * 128;

  bool is_sp = (MODE == 4) && (blockIdx.x < 4);
  int col0;
  const __bf16 *Abase, *Bbase;
  if (MODE == 4) {
    col0 = is_sp ? blockIdx.x * 128 : (blockIdx.x - 4) * 128;
    Abase = is_sp ? A : A2;
    Bbase = is_sp ? BT : BT2;
  } else {
    col0 = blockIdx.x * 128;
    Abase = A;
    Bbase = BT;
  }

  auto stage = [&](int buf, int k0) {
    int c = tid;
    gl_lds16(Abase + (size_t)(row0 + (c >> 2)) * K + k0 + (c & 3) * 8,
             (char*)smA[buf] + (tid >> 6) * 1024);
    gl_lds16(Bbase + (size_t)(col0 + (c >> 2)) * K + k0 + (c & 3) * 8,
             (char*)smB[buf] + (tid >> 6) * 1024);
  };

  stage(0, 0);
  __syncthreads();

  f32x4 acc[4][2] = {};
  int cur = 0;
  for (int k0 = 32; k0 <= K; k0 += 32) {
    if (k0 < K) stage(cur ^ 1, k0);
    bf16x8 a[4], b[2];
#pragma unroll
    for (int m = 0; m < 4; m++)
      a[m] = *reinterpret_cast<const bf16x8*>(smA[cur] + (wr + m * 16 + lr) * 32 + hi * 8);
#pragma unroll
    for (int n = 0; n < 2; n++)
      b[n] = *reinterpret_cast<const bf16x8*>(smB[cur] + (wc + n * 16 + lr) * 32 + hi * 8);
#pragma unroll
    for (int m = 0; m < 4; m++)
#pragma unroll
      for (int n = 0; n < 2; n++) acc[m][n] = MFMA16(a[m], b[n], acc[m][n]);
    __syncthreads();
    cur ^= 1;
  }

  int rb = hi * 4;
#pragma unroll
  for (int m = 0; m < 4; m++)
#pragma unroll
    for (int n = 0; n < 2; n++) {
      int col = col0 + wc + n * 16 + lr;
      float bia;
      if (MODE == 3) bia = (col >= 1024) ? bias2[col - 1024] : bias[col];
      else if (MODE == 4) bia = is_sp ? bias[col] : bias2[col];
      else bia = bias[col];
#pragma unroll
      for (int r = 0; r < 4; r++) {
        int row = row0 + wr + m * 16 + rb + r;
        float v = acc[m][n][r] + bia;
        if (MODE == 0) {
          out[(size_t)row * N + col] = (OutT)v;
        } else if (MODE == 3) {
          int bb = row >> 10, s = row & 1023;
          if (col < 1024) {
            int h = col >> 6, d = col & 63;
            out[(((size_t)(bb * H + h)) * S + s) * DEPTH + d] = (OutT)v;
          } else {
            int c2 = col - 1024, h = c2 >> 6, d = c2 & 63;
            out2[(((size_t)(bb * H + h)) * DEPTH + d) * S + s] = (OutT)v;
          }
        } else {  // MODE 4
          if (is_sp) {
            out[(size_t)row * 512 + col] = (OutT)fmaxf(v, 0.0f);
          } else {
            int bb = row >> 10, s = row & 1023, h = col >> 6, d = col & 63;
            out2[(((size_t)(bb * H + h)) * S + s) * DEPTH + d] = (OutT)v;
          }
        }
      }
    }
}

// ---------------- fused logits + softmax + PV: QBLK=32, 512 threads, XCD-local heads ----------------
// grid: (32, 64) = 2048 blocks; each XCD owns 8 consecutive bh.
// LDS: bf16 logits/P [32][1024] swizzled byte(q,k)=q*2048+((2k)^((q&7)<<4)) = 64 KB;
// PV partials f32 [8][32][64] alias it. No-max base-2 softmax.
// attn f32 store DEFERRED to after PV (from LDS P) so the 268 MB store burst
// drains under phases 4/5 + teardown; all barriers are lgkm-only (no vmem drain).
__global__ __launch_bounds__(512) void attn_fused(const __bf16* __restrict__ qh,
                                                  const __bf16* __restrict__ kh,
                                                  const __bf16* __restrict__ vhT,
                                                  const __bf16* __restrict__ maskb,
                                                  float* __restrict__ attn,
                                                  __bf16* __restrict__ concat) {
  __shared__ float4 smem4[4096];  // 64 KB
  char* sm = (char*)smem4;
  int tid = threadIdx.x, lane = tid & 63, wv = tid >> 6;  // wv 0..7
  int lr = lane & 15, hi = lane >> 4, lk = hi * 8;
  int rb = hi * 4;

  // XCD-aware remap: all 32 blocks of one bh land on one XCD.
  int lin = blockIdx.y * 32 + blockIdx.x;
  int xcd = lin & 7, idx = lin >> 3;
  int bh = xcd * 8 + (idx >> 5);
  int q0 = (idx & 31) * 32;
  int b = bh >> 4, h = bh & 15;

  const __bf16* qbase = qh + (size_t)bh * S * DEPTH;
  const __bf16* kbase = kh + (size_t)bh * S * DEPTH;
  const __bf16* vbase = vhT + (size_t)bh * DEPTH * S;

  // ---- Phase 0: prefetch this wave's 4 mask rows into regs (hides under QK^T) ----
  bf16x4 mk[4][4];
  {
    const __bf16* mrow0 = maskb + ((size_t)b * S + q0 + wv * 4) * S;
#pragma unroll
    for (int rr = 0; rr < 4; rr++)
#pragma unroll
      for (int j = 0; j < 4; j++)
        mk[rr][j] = *reinterpret_cast<const bf16x4*>(mrow0 + rr * S + j * 256 + lane * 4);
  }

  // ---- Phase 1: swapped QK^T -> logits*(0.125*log2e) in LDS ----
  constexpr float SCL = 0.125f * 1.4426950408889634f;
  bf16x8 aq[2][2];
#pragma unroll
  for (int qg = 0; qg < 2; qg++) {
    aq[qg][0] = *reinterpret_cast<const bf16x8*>(qbase + (q0 + qg * 16 + lr) * DEPTH + lk);
    aq[qg][1] = *reinterpret_cast<const bf16x8*>(qbase + (q0 + qg * 16 + lr) * DEPTH + 32 + lk);
  }
  int swzq = (lr & 7) << 4;
#pragma unroll 2
  for (int ct = 0; ct < 8; ct++) {
    int col0 = wv * 128 + ct * 16;
    bf16x8 b0 = *reinterpret_cast<const bf16x8*>(kbase + (col0 + lr) * DEPTH + lk);
    bf16x8 b1 = *reinterpret_cast<const bf16x8*>(kbase + (col0 + lr) * DEPTH + 32 + lk);
    __builtin_amdgcn_s_setprio(1);
#pragma unroll
    for (int qg = 0; qg < 2; qg++) {
      f32x4 acc = {};
      acc = MFMA16(b0, aq[qg][0], acc);
      acc = MFMA16(b1, aq[qg][1], acc);
      bf16x4 st = {(__bf16)(acc[0] * SCL), (__bf16)(acc[1] * SCL),
                   (__bf16)(acc[2] * SCL), (__bf16)(acc[3] * SCL)};
      int byte = (qg * 16 + lr) * 2048 + (((col0 + hi * 4) * 2) ^ swzq);
      *reinterpret_cast<bf16x4*>(sm + byte) = st;
    }
    __builtin_amdgcn_s_setprio(0);
  }
  bar_lds();

  // ---- Phase 2: no-max base-2 softmax; LDS-only (P bf16 back in place) ----
  for (int rr = 0; rr < 4; rr++) {
    int row = wv * 4 + rr;
    int base = row * 2048, swz = (row & 7) << 4;
    bf16x4 praw[4];
#pragma unroll
    for (int j = 0; j < 4; j++)
      praw[j] = *reinterpret_cast<const bf16x4*>(sm + base + ((j * 512 + lane * 8) ^ swz));
    float e[16], ssum = 0.f;
#pragma unroll
    for (int j = 0; j < 4; j++)
#pragma unroll
      for (int t = 0; t < 4; t++) {
        e[j * 4 + t] = exp2f((float)praw[j][t] + (float)mk[rr][j][t] * (-1e9f));
        ssum += e[j * 4 + t];
      }
    ssum = wave_sum(ssum);
    float inv = 1.0f / ssum;
#pragma unroll
    for (int j = 0; j < 4; j++) {
      bf16x4 pw = {(__bf16)(e[j * 4 + 0] * inv), (__bf16)(e[j * 4 + 1] * inv),
                   (__bf16)(e[j * 4 + 2] * inv), (__bf16)(e[j * 4 + 3] * inv)};
      *reinterpret_cast<bf16x4*>(sm + base + ((j * 512 + lane * 8) ^ swz)) = pw;
    }
  }
  bar_lds();

  // ---- Phase 3: PV; wave w owns k-chunk [128w,128w+128), both row-groups (V read once) ----
  f32x4 pacc[2][4] = {};
#pragma unroll
  for (int step = 0; step < 4; step++) {
    int k0 = wv * 128 + step * 32;
    bf16x8 vb[4];
#pragma unroll
    for (int t = 0; t < 4; t++)
      vb[t] = *reinterpret_cast<const bf16x8*>(vbase + (size_t)(t * 16 + lr) * S + k0 + lk);
    __builtin_amdgcn_s_setprio(1);
#pragma unroll
    for (int rg = 0; rg < 2; rg++) {
      int abyte = (rg * 16 + lr) * 2048 + (((k0 + hi * 8) * 2) ^ swzq);
      bf16x8 a = *reinterpret_cast<const bf16x8*>(sm + abyte);
#pragma unroll
      for (int t = 0; t < 4; t++) pacc[rg][t] = MFMA16(a, vb[t], pacc[rg][t]);
    }
    __builtin_amdgcn_s_setprio(0);
  }

  // ---- Phase 3.5: attn f32 store from LDS P (read-only reuse; drains under 4/5) ----
  float* abase = attn + (size_t)bh * S * S + (size_t)q0 * S;
  for (int rr = 0; rr < 4; rr++) {
    int row = wv * 4 + rr;
    int base = row * 2048, swz = (row & 7) << 4;
#pragma unroll
    for (int j = 0; j < 4; j++) {
      bf16x4 pw = *reinterpret_cast<const bf16x4*>(sm + base + ((j * 512 + lane * 8) ^ swz));
      f32x4 st = {(float)pw[0], (float)pw[1], (float)pw[2], (float)pw[3]};
      __builtin_nontemporal_store(
          st, reinterpret_cast<f32x4*>(abase + (size_t)row * S + j * 256 + lane * 4));
    }
  }
  bar_lds();

  // ---- Phase 4: partials to LDS f32 [8 kc][32 rows][64 cols] (overwrites P) ----
  float* fp = (float*)sm;
#pragma unroll
  for (int rg = 0; rg < 2; rg++)
#pragma unroll
    for (int t = 0; t < 4; t++)
#pragma unroll
      for (int r = 0; r < 4; r++)
        fp[wv * 2048 + (rg * 16 + rb + r) * 64 + t * 16 + lr] = pacc[rg][t][r];
  bar_lds();

  // ---- Phase 5: reduce over 8 kc + store ctx ----
  int row = tid >> 4;
  int c0 = (tid & 15) * 4;
  f32x4 sum = {};
#pragma unroll
  for (int w = 0; w < 8; w++) sum += *reinterpret_cast<f32x4*>(&fp[w * 2048 + row * 64 + c0]);
  __bf16* cdst = concat + ((size_t)b * S + q0 + row) * DM + h * DEPTH + c0;
  bf16x4 o = {(__bf16)sum[0], (__bf16)sum[1], (__bf16)sum[2], (__bf16)sum[3]};
  *reinterpret_cast<bf16x4*>(cdst) = o;
}

// ---------------- launch ----------------

extern "C" void kernel_launch(void* const* d_in, const int* in_sizes, int n_in,
                              void* d_out, int out_size, void* d_ws, size_t ws_size,
                              hipStream_t stream) {
  const float* q    = (const float*)d_in[0];
  const float* mdm  = (const float*)d_in[1];
  const float* mask = (const float*)d_in[2];
  const float* W_sp = (const float*)d_in[3];
  const float* b_sp = (const float*)d_in[4];
  const float* Wq   = (const float*)d_in[5];
  const float* bq   = (const float*)d_in[6];
  const float* Wk   = (const float*)d_in[7];
  const float* bk   = (const float*)d_in[8];
  const float* Wv   = (const float*)d_in[9];
  const float* bv   = (const float*)d_in[10];
  const float* Wo   = (const float*)d_in[11];
  const float* bo   = (const float*)d_in[12];

  char* p = (char*)d_ws;
  __bf16* WspT   = (__bf16*)p; p += (size_t)524288 * 2;
  __bf16* WkT    = (__bf16*)p; p += (size_t)524288 * 2;   // keep WkT/WvT adjacent!
  __bf16* WvT    = (__bf16*)p; p += (size_t)524288 * 2;
  __bf16* WqT    = (__bf16*)p; p += (size_t)1048576 * 2;
  __bf16* WoT    = (__bf16*)p; p += (size_t)1048576 * 2;
  __bf16* sp     = (__bf16*)p; p += (size_t)2097152 * 2;
  __bf16* qh     = (__bf16*)p; p += (size_t)4194304 * 2;
  __bf16* kh     = (__bf16*)p; p += (size_t)4194304 * 2;
  __bf16* vhT    = (__bf16*)p; p += (size_t)4194304 * 2;
  __bf16* concat = (__bf16*)p; p += (size_t)4194304 * 2;
  __bf16* mdm_b  = (__bf16*)p; p += (size_t)4194304 * 2;
  __bf16* q_b    = (__bf16*)p; p += (size_t)4194304 * 2;
  __bf16* maskb  = (__bf16*)p; p += (size_t)4194304 * 2;

  float* out_p  = (float*)d_out;
  float* attn_p = (float*)d_out + (size_t)4194304;

  // casts (mdm, q, mask) + weight transposes: 6144 + 896 = 7040 blocks
  prep<<<7040, 256, 0, stream>>>(mdm, q, mask, W_sp, Wq, Wk, Wv, Wo,
                                 mdm_b, q_b, maskb, WspT, WqT, WkT, WvT, WoT);

  // sp = relu(mdm@Wsp+b) [4096,512] bf16  +  qh = split_heads(q@Wq+bq), fused
  gemmL8<1024, 4, __bf16><<<dim3(12, 32), 512, 0, stream>>>(
      mdm_b, q_b, WspT, WqT, b_sp, bq, sp, qh, 512);

  // kh + vhT fused (B panel = [WkT;WvT] = [2048,512])
  gemmL8<512, 3, __bf16><<<dim3(16, 32), 512, 0, stream>>>(
      sp, nullptr, WkT, nullptr, bk, bv, kh, vhT, 2048);

  // fused: attn (f32, d_out) + ctx -> concat
  attn_fused<<<dim3(32, 64), 512, 0, stream>>>(qh, kh, vhT, maskb, attn_p, concat);

  // out = concat @ Wo + bo -> d_out (f32)
  gemmL8<1024, 0, float><<<dim3(8, 32), 512, 0, stream>>>(
      concat, nullptr, WoT, nullptr, bo, nullptr, out_p, nullptr, 1024);
}

// Round 13
// 195.036 us; speedup vs baseline: 1.0394x; 1.0394x over previous
//
#include <hip/hip_runtime.h>
#include <hip/hip_bf16.h>
#include <cmath>

// B=4, S=1024, D_MODEL=1024, H=16, D_SP=512, DEPTH=64
// Inputs f32; outputs f32: out [4,1024,1024] then attn [4,16,1024,1024].

typedef __bf16 bf16x8 __attribute__((ext_vector_type(8)));
typedef __bf16 bf16x4 __attribute__((ext_vector_type(4)));
typedef float  f32x4  __attribute__((ext_vector_type(4)));

#define MFMA16(a, b, c) __builtin_amdgcn_mfma_f32_16x16x32_bf16((a), (b), (c), 0, 0, 0)

static constexpr int S = 1024, DM = 1024, H = 16, DEPTH = 64;

__device__ inline float wave_sum(float v) {
#pragma unroll
  for (int o = 32; o > 0; o >>= 1) v += __shfl_xor(v, o);
  return v;
}

__device__ inline bf16x8 cvt8(const float* p) {
  float4 f0 = *reinterpret_cast<const float4*>(p);
  float4 f1 = *reinterpret_cast<const float4*>(p + 4);
  bf16x8 a = {(__bf16)f0.x, (__bf16)f0.y, (__bf16)f0.z, (__bf16)f0.w,
              (__bf16)f1.x, (__bf16)f1.y, (__bf16)f1.z, (__bf16)f1.w};
  return a;
}

// async global->LDS, 16 bytes per lane; lds dest = wave-uniform base + lane*16
__device__ inline void gl_lds16(const __bf16* g, void* l) {
  __builtin_amdgcn_global_load_lds(
      (const __attribute__((address_space(1))) unsigned int*)g,
      (__attribute__((address_space(3))) unsigned int*)l, 16, 0, 0);
}

// ---------------- prep: mdm/q/mask casts + all weight transposes ----------------
// blocks: 6144 casts + 896 transposes = 7040 total.
__device__ inline void tr_body(const float* __restrict__ W, __bf16* __restrict__ WT,
                               int K, int N, int bx, int by) {
  __shared__ float tile[64][65];
  int k0 = bx * 64, n0 = by * 64;
  int t = threadIdx.x;
  int r = t >> 2, c4 = (t & 3) * 16;
  const float* src = W + (size_t)(k0 + r) * N + n0 + c4;
#pragma unroll
  for (int j = 0; j < 4; j++) {
    float4 v = *reinterpret_cast<const float4*>(src + j * 4);
    tile[r][c4 + j * 4 + 0] = v.x;
    tile[r][c4 + j * 4 + 1] = v.y;
    tile[r][c4 + j * 4 + 2] = v.z;
    tile[r][c4 + j * 4 + 3] = v.w;
  }
  __syncthreads();
  __bf16* dst = WT + (size_t)(n0 + r) * K + k0 + c4;
  bf16x8 o0, o1;
#pragma unroll
  for (int j = 0; j < 8; j++) {
    o0[j] = (__bf16)tile[c4 + j][r];
    o1[j] = (__bf16)tile[c4 + 8 + j][r];
  }
  *reinterpret_cast<bf16x8*>(dst) = o0;
  *reinterpret_cast<bf16x8*>(dst + 8) = o1;
}

__global__ __launch_bounds__(256) void prep(
    const float* __restrict__ mdm, const float* __restrict__ q,
    const float* __restrict__ mask, const float* __restrict__ Wsp,
    const float* __restrict__ Wq, const float* __restrict__ Wk,
    const float* __restrict__ Wv, const float* __restrict__ Wo, __bf16* mdm_b,
    __bf16* q_b, __bf16* maskb, __bf16* WspT, __bf16* WqT, __bf16* WkT,
    __bf16* WvT, __bf16* WoT) {
  int id = blockIdx.x;
  if (id < 6144) {
    int i = id * 256 + threadIdx.x;
    if (i < 524288) {
      *reinterpret_cast<bf16x8*>(mdm_b + (size_t)i * 8) = cvt8(mdm + (size_t)i * 8);
    } else if (i < 1048576) {
      int j = i - 524288;
      *reinterpret_cast<bf16x8*>(q_b + (size_t)j * 8) = cvt8(q + (size_t)j * 8);
    } else {
      int j = i - 1048576;
      *reinterpret_cast<bf16x8*>(maskb + (size_t)j * 8) = cvt8(mask + (size_t)j * 8);
    }
    return;
  }
  id -= 6144;
  if (id < 128)      tr_body(Wsp, WspT, 1024, 512, id & 15, id >> 4);
  else if (id < 384) { id -= 128; tr_body(Wq, WqT, 1024, 1024, id & 15, id >> 4); }
  else if (id < 512) { id -= 384; tr_body(Wk, WkT, 512, 1024, id & 7, id >> 3); }
  else if (id < 640) { id -= 512; tr_body(Wv, WvT, 512, 1024, id & 7, id >> 3); }
  else               { id -= 640; tr_body(Wo, WoT, 1024, 1024, id & 15, id >> 4); }
}

// ---------------- pipelined LDS-staged GEMM, 512 threads (8 waves, 2x4 of 64x32) ----------------
// TM=128, TN=128, BK=32, double-buffered, 1 barrier/K-step.
// MODE 0: row-major out, bias. MODE 3: B rows<1024 -> kh (head-split), else vhT.
// MODE 4: blockIdx.x<4: sp=relu(A@BT) N=512; else qh from A2@BT2 (head-split).
template <int K, int MODE, typename OutT>
__global__ __launch_bounds__(512) void gemmL8(const __bf16* __restrict__ A,
                                              const __bf16* __restrict__ A2,
                                              const __bf16* __restrict__ BT,
                                              const __bf16* __restrict__ BT2,
                                              const float* __restrict__ bias,
                                              const float* __restrict__ bias2,
                                              OutT* __restrict__ out,
                                              OutT* __restrict__ out2, int N) {
  __shared__ __bf16 smA[2][128 * 32];
  __shared__ __bf16 smB[2][128 * 32];
  int tid = threadIdx.x, lane = tid & 63, wv = tid >> 6;
  int lr = lane & 15, hi = lane >> 4;
  int wr = (wv >> 2) * 64, wc = (wv & 3) * 32;
  int row0 = blockIdx.y * 128;

  bool is_sp = (MODE == 4) && (blockIdx.x < 4);
  int col0;
  const __bf16 *Abase, *Bbase;
  if (MODE == 4) {
    col0 = is_sp ? blockIdx.x * 128 : (blockIdx.x - 4) * 128;
    Abase = is_sp ? A : A2;
    Bbase = is_sp ? BT : BT2;
  } else {
    col0 = blockIdx.x * 128;
    Abase = A;
    Bbase = BT;
  }

  auto stage = [&](int buf, int k0) {
    int c = tid;
    gl_lds16(Abase + (size_t)(row0 + (c >> 2)) * K + k0 + (c & 3) * 8,
             (char*)smA[buf] + (tid >> 6) * 1024);
    gl_lds16(Bbase + (size_t)(col0 + (c >> 2)) * K + k0 + (c & 3) * 8,
             (char*)smB[buf] + (tid >> 6) * 1024);
  };

  stage(0, 0);
  __syncthreads();

  f32x4 acc[4][2] = {};
  int cur = 0;
  for (int k0 = 32; k0 <= K; k0 += 32) {
    if (k0 < K) stage(cur ^ 1, k0);
    bf16x8 a[4], b[2];
#pragma unroll
    for (int m = 0; m < 4; m++)
      a[m] = *reinterpret_cast<const bf16x8*>(smA[cur] + (wr + m * 16 + lr) * 32 + hi * 8);
#pragma unroll
    for (int n = 0; n < 2; n++)
      b[n] = *reinterpret_cast<const bf16x8*>(smB[cur] + (wc + n * 16 + lr) * 32 + hi * 8);
#pragma unroll
    for (int m = 0; m < 4; m++)
#pragma unroll
      for (int n = 0; n < 2; n++) acc[m][n] = MFMA16(a[m], b[n], acc[m][n]);
    __syncthreads();
    cur ^= 1;
  }

  int rb = hi * 4;
#pragma unroll
  for (int m = 0; m < 4; m++)
#pragma unroll
    for (int n = 0; n < 2; n++) {
      int col = col0 + wc + n * 16 + lr;
      float bia;
      if (MODE == 3) bia = (col >= 1024) ? bias2[col - 1024] : bias[col];
      else if (MODE == 4) bia = is_sp ? bias[col] : bias2[col];
      else bia = bias[col];
#pragma unroll
      for (int r = 0; r < 4; r++) {
        int row = row0 + wr + m * 16 + rb + r;
        float v = acc[m][n][r] + bia;
        if (MODE == 0) {
          out[(size_t)row * N + col] = (OutT)v;
        } else if (MODE == 3) {
          int bb = row >> 10, s = row & 1023;
          if (col < 1024) {
            int h = col >> 6, d = col & 63;
            out[(((size_t)(bb * H + h)) * S + s) * DEPTH + d] = (OutT)v;
          } else {
            int c2 = col - 1024, h = c2 >> 6, d = c2 & 63;
            out2[(((size_t)(bb * H + h)) * DEPTH + d) * S + s] = (OutT)v;
          }
        } else {  // MODE 4
          if (is_sp) {
            out[(size_t)row * 512 + col] = (OutT)fmaxf(v, 0.0f);
          } else {
            int bb = row >> 10, s = row & 1023, h = col >> 6, d = col & 63;
            out2[(((size_t)(bb * H + h)) * S + s) * DEPTH + d] = (OutT)v;
          }
        }
      }
    }
}

// ---------------- fused logits + softmax + PV: QBLK=32, 512 threads, XCD-local heads ----------------
// grid: (32, 64) = 2048 blocks; each XCD owns 8 consecutive bh.
// LDS: bf16 logits/P [32][1024] swizzled byte(q,k)=q*2048+((2k)^((q&7)<<4)) = 64 KB;
// PV partials f32 [8][32][64] alias it. No-max softmax (logits bounded; exp(-1e9)=0).
__global__ __launch_bounds__(512) void attn_fused(const __bf16* __restrict__ qh,
                                                  const __bf16* __restrict__ kh,
                                                  const __bf16* __restrict__ vhT,
                                                  const __bf16* __restrict__ maskb,
                                                  float* __restrict__ attn,
                                                  __bf16* __restrict__ concat) {
  __shared__ float4 smem4[4096];  // 64 KB
  char* sm = (char*)smem4;
  int tid = threadIdx.x, lane = tid & 63, wv = tid >> 6;  // wv 0..7
  int lr = lane & 15, hi = lane >> 4, lk = hi * 8;
  int rb = hi * 4;

  // XCD-aware remap: all 32 blocks of one bh land on one XCD.
  int lin = blockIdx.y * 32 + blockIdx.x;
  int xcd = lin & 7, idx = lin >> 3;
  int bh = xcd * 8 + (idx >> 5);
  int q0 = (idx & 31) * 32;
  int b = bh >> 4, h = bh & 15;

  const __bf16* qbase = qh + (size_t)bh * S * DEPTH;
  const __bf16* kbase = kh + (size_t)bh * S * DEPTH;
  const __bf16* vbase = vhT + (size_t)bh * DEPTH * S;

  // ---- Phase 1: swapped QK^T; wave w covers k in [128w,128w+128) for both q-groups ----
  bf16x8 aq[2][2];
#pragma unroll
  for (int qg = 0; qg < 2; qg++) {
    aq[qg][0] = *reinterpret_cast<const bf16x8*>(qbase + (q0 + qg * 16 + lr) * DEPTH + lk);
    aq[qg][1] = *reinterpret_cast<const bf16x8*>(qbase + (q0 + qg * 16 + lr) * DEPTH + 32 + lk);
  }
  int swzq = (lr & 7) << 4;
#pragma unroll 2
  for (int ct = 0; ct < 8; ct++) {
    int col0 = wv * 128 + ct * 16;
    bf16x8 b0 = *reinterpret_cast<const bf16x8*>(kbase + (col0 + lr) * DEPTH + lk);
    bf16x8 b1 = *reinterpret_cast<const bf16x8*>(kbase + (col0 + lr) * DEPTH + 32 + lk);
    __builtin_amdgcn_s_setprio(1);
#pragma unroll
    for (int qg = 0; qg < 2; qg++) {
      f32x4 acc = {};
      acc = MFMA16(b0, aq[qg][0], acc);
      acc = MFMA16(b1, aq[qg][1], acc);
      bf16x4 st = {(__bf16)(acc[0] * 0.125f), (__bf16)(acc[1] * 0.125f),
                   (__bf16)(acc[2] * 0.125f), (__bf16)(acc[3] * 0.125f)};
      int byte = (qg * 16 + lr) * 2048 + (((col0 + hi * 4) * 2) ^ swzq);
      *reinterpret_cast<bf16x4*>(sm + byte) = st;
    }
    __builtin_amdgcn_s_setprio(0);
  }
  __syncthreads();

  // ---- Phase 2: no-max softmax; wave w owns rows 4w..4w+3 ----
  float* abase = attn + (size_t)bh * S * S + (size_t)q0 * S;
  for (int rr = 0; rr < 4; rr++) {
    int row = wv * 4 + rr;
    int base = row * 2048, swz = (row & 7) << 4;
    const __bf16* mrow = maskb + ((size_t)b * S + q0 + row) * S;
    bf16x4 praw[4], mk[4];
#pragma unroll
    for (int j = 0; j < 4; j++) {
      praw[j] = *reinterpret_cast<const bf16x4*>(sm + base + ((j * 512 + lane * 8) ^ swz));
      mk[j] = *reinterpret_cast<const bf16x4*>(mrow + j * 256 + lane * 4);
    }
    float e[16], ssum = 0.f;
#pragma unroll
    for (int j = 0; j < 4; j++)
#pragma unroll
      for (int t = 0; t < 4; t++) {
        e[j * 4 + t] = __expf((float)praw[j][t] + (float)mk[j][t] * (-1e9f));
        ssum += e[j * 4 + t];
      }
    ssum = wave_sum(ssum);
    float inv = 1.0f / ssum;
#pragma unroll
    for (int j = 0; j < 4; j++) {
      f32x4 st = {e[j * 4 + 0] * inv, e[j * 4 + 1] * inv, e[j * 4 + 2] * inv, e[j * 4 + 3] * inv};
      // LDS P-write first (PV depends on it), fire-and-forget HBM store second.
      bf16x4 pw = {(__bf16)st[0], (__bf16)st[1], (__bf16)st[2], (__bf16)st[3]};
      *reinterpret_cast<bf16x4*>(sm + base + ((j * 512 + lane * 8) ^ swz)) = pw;
      __builtin_nontemporal_store(
          st, reinterpret_cast<f32x4*>(abase + (size_t)row * S + j * 256 + lane * 4));
    }
  }
  __syncthreads();

  // ---- Phase 3: PV; wave w owns k-chunk [128w,128w+128), both row-groups (V read once) ----
  f32x4 pacc[2][4] = {};
#pragma unroll
  for (int step = 0; step < 4; step++) {
    int k0 = wv * 128 + step * 32;
    bf16x8 vb[4];
#pragma unroll
    for (int t = 0; t < 4; t++)
      vb[t] = *reinterpret_cast<const bf16x8*>(vbase + (size_t)(t * 16 + lr) * S + k0 + lk);
    __builtin_amdgcn_s_setprio(1);
#pragma unroll
    for (int rg = 0; rg < 2; rg++) {
      int abyte = (rg * 16 + lr) * 2048 + (((k0 + hi * 8) * 2) ^ swzq);
      bf16x8 a = *reinterpret_cast<const bf16x8*>(sm + abyte);
#pragma unroll
      for (int t = 0; t < 4; t++) pacc[rg][t] = MFMA16(a, vb[t], pacc[rg][t]);
    }
    __builtin_amdgcn_s_setprio(0);
  }
  __syncthreads();

  // ---- Phase 4: partials to LDS f32 [8 kc][32 rows][64 cols] ----
  float* fp = (float*)sm;
#pragma unroll
  for (int rg = 0; rg < 2; rg++)
#pragma unroll
    for (int t = 0; t < 4; t++)
#pragma unroll
      for (int r = 0; r < 4; r++)
        fp[wv * 2048 + (rg * 16 + rb + r) * 64 + t * 16 + lr] = pacc[rg][t][r];
  __syncthreads();

  // ---- Phase 5: reduce over 8 kc + store ctx ----
  int row = tid >> 4;
  int c0 = (tid & 15) * 4;
  f32x4 sum = {};
#pragma unroll
  for (int w = 0; w < 8; w++) sum += *reinterpret_cast<f32x4*>(&fp[w * 2048 + row * 64 + c0]);
  __bf16* cdst = concat + ((size_t)b * S + q0 + row) * DM + h * DEPTH + c0;
  bf16x4 o = {(__bf16)sum[0], (__bf16)sum[1], (__bf16)sum[2], (__bf16)sum[3]};
  *reinterpret_cast<bf16x4*>(cdst) = o;
}

// ---------------- launch ----------------

extern "C" void kernel_launch(void* const* d_in, const int* in_sizes, int n_in,
                              void* d_out, int out_size, void* d_ws, size_t ws_size,
                              hipStream_t stream) {
  const float* q    = (const float*)d_in[0];
  const float* mdm  = (const float*)d_in[1];
  const float* mask = (const float*)d_in[2];
  const float* W_sp = (const float*)d_in[3];
  const float* b_sp = (const float*)d_in[4];
  const float* Wq   = (const float*)d_in[5];
  const float* bq   = (const float*)d_in[6];
  const float* Wk   = (const float*)d_in[7];
  const float* bk   = (const float*)d_in[8];
  const float* Wv   = (const float*)d_in[9];
  const float* bv   = (const float*)d_in[10];
  const float* Wo   = (const float*)d_in[11];
  const float* bo   = (const float*)d_in[12];

  char* p = (char*)d_ws;
  __bf16* WspT   = (__bf16*)p; p += (size_t)524288 * 2;
  __bf16* WkT    = (__bf16*)p; p += (size_t)524288 * 2;   // keep WkT/WvT adjacent!
  __bf16* WvT    = (__bf16*)p; p += (size_t)524288 * 2;
  __bf16* WqT    = (__bf16*)p; p += (size_t)1048576 * 2;
  __bf16* WoT    = (__bf16*)p; p += (size_t)1048576 * 2;
  __bf16* sp     = (__bf16*)p; p += (size_t)2097152 * 2;
  __bf16* qh     = (__bf16*)p; p += (size_t)4194304 * 2;
  __bf16* kh     = (__bf16*)p; p += (size_t)4194304 * 2;
  __bf16* vhT    = (__bf16*)p; p += (size_t)4194304 * 2;
  __bf16* concat = (__bf16*)p; p += (size_t)4194304 * 2;
  __bf16* mdm_b  = (__bf16*)p; p += (size_t)4194304 * 2;
  __bf16* q_b    = (__bf16*)p; p += (size_t)4194304 * 2;
  __bf16* maskb  = (__bf16*)p; p += (size_t)4194304 * 2;

  float* out_p  = (float*)d_out;
  float* attn_p = (float*)d_out + (size_t)4194304;

  // casts (mdm, q, mask) + weight transposes: 6144 + 896 = 7040 blocks
  prep<<<7040, 256, 0, stream>>>(mdm, q, mask, W_sp, Wq, Wk, Wv, Wo,
                                 mdm_b, q_b, maskb, WspT, WqT, WkT, WvT, WoT);

  // sp = relu(mdm@Wsp+b) [4096,512] bf16  +  qh = split_heads(q@Wq+bq), fused
  gemmL8<1024, 4, __bf16><<<dim3(12, 32), 512, 0, stream>>>(
      mdm_b, q_b, WspT, WqT, b_sp, bq, sp, qh, 512);

  // kh + vhT fused (B panel = [WkT;WvT] = [2048,512])
  gemmL8<512, 3, __bf16><<<dim3(16, 32), 512, 0, stream>>>(
      sp, nullptr, WkT, nullptr, bk, bv, kh, vhT, 2048);

  // fused: attn (f32, d_out) + ctx -> concat
  attn_fused<<<dim3(32, 64), 512, 0, stream>>>(qh, kh, vhT, maskb, attn_p, concat);

  // out = concat @ Wo + bo -> d_out (f32)
  gemmL8<1024, 0, float><<<dim3(8, 32), 512, 0, stream>>>(
      concat, nullptr, WoT, nullptr, bo, nullptr, out_p, nullptr, 1024);
}